// Round 5
// baseline (318.792 us; speedup 1.0000x reference)
//
#include <hip/hip_runtime.h>
#include <math.h>

// BPCAPooling per batch [128,128,64]:
//   patches[262144,4] where column j = channel%4 (each aligned float4 of input
//   is one patches row). Normalize columns by mean/std, gram = P^T P, top
//   eigenvector v (sign-fixed), out = P_norm @ v -> [64,64,64].
//
// Pipeline (2 real kernels + 128B memset):
//   memset: zero 32 per-batch completion counters in ws
//   stats_kernel: 2048 blocks; per-block 14 f64 moment partials -> ws; the
//     LAST block of each batch (fence-counter) reduces 64 partials and runs
//     the 4x4 f64 Jacobi on lane 0, emitting projection weights wb.
//   proj_kernel: out = w.x + bias, fully coalesced float4 (input rides L3).

#define NBATCH 32
#define N_PER_BATCH (128 * 128 * 64)          // 1,048,576 floats
#define ROWS_PER_BATCH (N_PER_BATCH / 4)      // 262,144 rows of 4
#define BLOCKS_PER_BATCH 64
#define ROWS_PER_BLOCK (ROWS_PER_BATCH / BLOCKS_PER_BATCH)  // 4096
#define ROWS_PER_THREAD (ROWS_PER_BLOCK / 256)              // 16

// ws layout:
//   [0, 2048*14*8)     double partials[2048][14]
//   [CNT_OFFSET,+128)  uint   counters[32]
//   [WB_OFFSET,+1024)  float  wb[32][8]: w0..w3, bias
#define CNT_OFFSET (2048 * 14 * 8)
#define WB_OFFSET (CNT_OFFSET + 128)

__device__ inline double wave_reduce_add(double v) {
    #pragma unroll
    for (int off = 32; off > 0; off >>= 1) v += __shfl_down(v, off, 64);
    return v;
}

__global__ __launch_bounds__(256, 4) void stats_kernel(const float* __restrict__ in,
                                                       double* __restrict__ partials,
                                                       unsigned int* __restrict__ counters,
                                                       float* __restrict__ wb) {
    const int batch = blockIdx.x / BLOCKS_PER_BATCH;
    const int chunk = blockIdx.x % BLOCKS_PER_BATCH;
    const float4* src = (const float4*)(in + (size_t)batch * N_PER_BATCH);
    const int base = chunk * ROWS_PER_BLOCK + threadIdx.x;

    double s0 = 0, s1 = 0, s2 = 0, s3 = 0;
    double p00 = 0, p01 = 0, p02 = 0, p03 = 0;
    double p11 = 0, p12 = 0, p13 = 0;
    double p22 = 0, p23 = 0, p33 = 0;

    #pragma unroll 4
    for (int k = 0; k < ROWS_PER_THREAD; ++k) {
        float4 v = src[base + k * 256];
        double a = (double)v.x, b = (double)v.y, c = (double)v.z, d = (double)v.w;
        s0 += a; s1 += b; s2 += c; s3 += d;
        p00 += a * a; p01 += a * b; p02 += a * c; p03 += a * d;
        p11 += b * b; p12 += b * c; p13 += b * d;
        p22 += c * c; p23 += c * d; p33 += d * d;
    }

    double vals[14] = {s0, s1, s2, s3, p00, p01, p02, p03, p11, p12, p13, p22, p23, p33};
    __shared__ double red[4][14];
    __shared__ int is_last;
    const int lane = threadIdx.x & 63;
    const int wave = threadIdx.x >> 6;
    #pragma unroll
    for (int i = 0; i < 14; ++i) {
        double r = wave_reduce_add(vals[i]);
        if (lane == 0) red[wave][i] = r;
    }
    __syncthreads();
    if (threadIdx.x < 14) {
        partials[(size_t)blockIdx.x * 14 + threadIdx.x] =
            red[0][threadIdx.x] + red[1][threadIdx.x] +
            red[2][threadIdx.x] + red[3][threadIdx.x];
        __threadfence();   // release this block's partial (device scope)
    }
    __syncthreads();
    if (threadIdx.x == 0) {
        unsigned int old = atomicAdd(&counters[batch], 1u);
        is_last = (old == BLOCKS_PER_BATCH - 1);
    }
    __syncthreads();
    if (!is_last || threadIdx.x >= 64) return;

    // ---- last block for this batch: reduce 64 partials + Jacobi ----
    __threadfence();       // acquire: invalidate stale cached partials
    const double* p = partials + ((size_t)batch * BLOCKS_PER_BATCH + lane) * 14;
    double a[14];
    #pragma unroll
    for (int i = 0; i < 14; ++i) a[i] = wave_reduce_add(p[i]);

    if (lane != 0) return;

    const double N = (double)ROWS_PER_BATCH;
    double sum[4] = {a[0], a[1], a[2], a[3]};
    double S[4][4];
    S[0][0] = a[4];  S[0][1] = S[1][0] = a[5];  S[0][2] = S[2][0] = a[6];  S[0][3] = S[3][0] = a[7];
    S[1][1] = a[8];  S[1][2] = S[2][1] = a[9];  S[1][3] = S[3][1] = a[10];
    S[2][2] = a[11]; S[2][3] = S[3][2] = a[12]; S[3][3] = a[13];

    double m[4], sd[4], dn[4];
    #pragma unroll
    for (int j = 0; j < 4; ++j) {
        m[j] = sum[j] / N;
        double var = S[j][j] / N - m[j] * m[j];
        if (var < 0.0) var = 0.0;
        sd[j] = sqrt(var);
        dn[j] = (sd[j] == 0.0) ? 1.0 : sd[j];
    }

    // A = gram / N of normalized columns; zero row/col where std==0
    double A[4][4];
    #pragma unroll
    for (int j = 0; j < 4; ++j)
        #pragma unroll
        for (int k = 0; k < 4; ++k) {
            if (sd[j] == 0.0 || sd[k] == 0.0) A[j][k] = 0.0;
            else A[j][k] = (S[j][k] / N - m[j] * m[k]) / (dn[j] * dn[k]);
        }

    // Cyclic Jacobi, f64, 4 sweeps (A = I + E, |E|~2e-3: quadratic convergence)
    double V[4][4] = {{1, 0, 0, 0}, {0, 1, 0, 0}, {0, 0, 1, 0}, {0, 0, 0, 1}};
    for (int sweep = 0; sweep < 4; ++sweep) {
        for (int pp = 0; pp < 3; ++pp) {
            for (int q = pp + 1; q < 4; ++q) {
                double apq = A[pp][q];
                if (fabs(apq) < 1e-300) continue;
                double theta = (A[q][q] - A[pp][pp]) / (2.0 * apq);
                double t = copysign(1.0, theta) / (fabs(theta) + sqrt(theta * theta + 1.0));
                double c = 1.0 / sqrt(t * t + 1.0);
                double s = t * c;
                for (int k = 0; k < 4; ++k) {
                    double t1 = A[k][pp], t2 = A[k][q];
                    A[k][pp] = c * t1 - s * t2;
                    A[k][q]  = s * t1 + c * t2;
                }
                for (int k = 0; k < 4; ++k) {
                    double t1 = A[pp][k], t2 = A[q][k];
                    A[pp][k] = c * t1 - s * t2;
                    A[q][k]  = s * t1 + c * t2;
                }
                for (int k = 0; k < 4; ++k) {
                    double t1 = V[k][pp], t2 = V[k][q];
                    V[k][pp] = c * t1 - s * t2;
                    V[k][q]  = s * t1 + c * t2;
                }
            }
        }
    }

    int jmax = 0;
    double emax = A[0][0];
    for (int j = 1; j < 4; ++j)
        if (A[j][j] > emax) { emax = A[j][j]; jmax = j; }
    double v[4] = {V[0][jmax], V[1][jmax], V[2][jmax], V[3][jmax]};
    double sv = v[0] + v[1] + v[2] + v[3];
    if (sv < 0.0) { v[0] = -v[0]; v[1] = -v[1]; v[2] = -v[2]; v[3] = -v[3]; }

    double w[4], bias = 0.0;
    #pragma unroll
    for (int j = 0; j < 4; ++j) {
        w[j] = (sd[j] == 0.0) ? 0.0 : v[j] / dn[j];
        bias -= w[j] * m[j];
    }
    float* o = wb + batch * 8;
    o[0] = (float)w[0]; o[1] = (float)w[1]; o[2] = (float)w[2]; o[3] = (float)w[3];
    o[4] = (float)bias;
    // kernel completion flushes caches; proj kernel (next dispatch) sees wb.
}

// One thread -> 4 consecutive output channels (one float4 store),
// consuming 16 consecutive input channels (4 float4 loads, 64B contiguous).
__global__ __launch_bounds__(256) void proj_kernel(const float* __restrict__ in,
                                                   const float* __restrict__ wb,
                                                   float4* __restrict__ out) {
    const int t = blockIdx.x * 256 + threadIdx.x;   // 2,097,152 threads
    const int b  = t >> 16;                          // 65536 float4-outputs per batch
    const int r4 = t & 65535;
    const int i0 = r4 >> 10;                         // pooled row
    const int i1 = (r4 >> 4) & 63;                   // pooled col
    const int c0 = (r4 & 15) * 4;                    // first output channel
    const int i2 = c0 >> 5;
    const int i3 = (c0 >> 4) & 1;
    const int g0 = c0 & 15;                          // channel-group start

    const float* src = in + (size_t)(((b * 128 + 2 * i0 + i2) * 128) + (2 * i1 + i3)) * 64
                          + 4 * g0;
    const float4* s4 = (const float4*)src;
    float4 x0 = s4[0], x1 = s4[1], x2 = s4[2], x3 = s4[3];

    const float* p = wb + b * 8;
    float w0 = p[0], w1 = p[1], w2 = p[2], w3 = p[3], bias = p[4];

    float4 o;
    o.x = fmaf(w0, x0.x, fmaf(w1, x0.y, fmaf(w2, x0.z, fmaf(w3, x0.w, bias))));
    o.y = fmaf(w0, x1.x, fmaf(w1, x1.y, fmaf(w2, x1.z, fmaf(w3, x1.w, bias))));
    o.z = fmaf(w0, x2.x, fmaf(w1, x2.y, fmaf(w2, x2.z, fmaf(w3, x2.w, bias))));
    o.w = fmaf(w0, x3.x, fmaf(w1, x3.y, fmaf(w2, x3.z, fmaf(w3, x3.w, bias))));
    out[t] = o;
}

extern "C" void kernel_launch(void* const* d_in, const int* in_sizes, int n_in,
                              void* d_out, int out_size, void* d_ws, size_t ws_size,
                              hipStream_t stream) {
    const float* in = (const float*)d_in[0];
    float4* out = (float4*)d_out;
    double* partials = (double*)d_ws;
    unsigned int* counters = (unsigned int*)((char*)d_ws + CNT_OFFSET);
    float* wb = (float*)((char*)d_ws + WB_OFFSET);

    hipMemsetAsync(counters, 0, NBATCH * sizeof(unsigned int), stream);
    stats_kernel<<<NBATCH * BLOCKS_PER_BATCH, 256, 0, stream>>>(in, partials, counters, wb);
    proj_kernel<<<(NBATCH * ROWS_PER_BATCH / 4) / 256, 256, 0, stream>>>(in, wb, (float4*)out);
}

// Round 6
// 245.793 us; speedup vs baseline: 1.2970x; 1.2970x over previous
//
#include <hip/hip_runtime.h>
#include <math.h>

// BPCAPooling per batch [128,128,64]:
//   patches[262144,4] where column j = channel%4 (each aligned float4 of input
//   is one patches row). Normalize columns by mean/std, gram = P^T P, top
//   eigenvector v (sign-fixed), out = P_norm @ v -> [64,64,64].
//
// Pipeline (3 dispatches — R5 lesson: per-block device-scope __threadfence on
// gfx950 costs ~135us (2048 L2 writebacks); kernel boundaries are ONE flush):
//   stats_kernel: 2048 blocks, per-block partial sums (14 f64) -> ws
//   eigen_kernel: 32 blocks (1/batch): wave-reduce 64 partials; lane0 runs
//     f32 Jacobi on E = A - I (same eigvecs; all entries ~2e-3 scale so f32
//     is plenty; hw rcp/sqrt vs f64 soft-div cuts serial chain ~3us -> 0.6us)
//   proj_kernel:  out = w.x + bias, fully coalesced float4 (input rides L3)

#define NBATCH 32
#define N_PER_BATCH (128 * 128 * 64)          // 1,048,576 floats
#define ROWS_PER_BATCH (N_PER_BATCH / 4)      // 262,144 rows of 4
#define BLOCKS_PER_BATCH 64
#define ROWS_PER_BLOCK (ROWS_PER_BATCH / BLOCKS_PER_BATCH)  // 4096
#define ROWS_PER_THREAD (ROWS_PER_BLOCK / 256)              // 16

// ws layout:
//   [0, 2048*14*8)              double partials[2048][14]
//   [WB_OFFSET, +32*8*4)        float  wb[32][8]: w0..w3, bias
#define WB_OFFSET (2048 * 14 * 8)

__device__ inline double wave_reduce_add(double v) {
    #pragma unroll
    for (int off = 32; off > 0; off >>= 1) v += __shfl_down(v, off, 64);
    return v;
}

__global__ __launch_bounds__(256) void stats_kernel(const float* __restrict__ in,
                                                    double* __restrict__ partials) {
    const int batch = blockIdx.x / BLOCKS_PER_BATCH;
    const int chunk = blockIdx.x % BLOCKS_PER_BATCH;
    const float4* src = (const float4*)(in + (size_t)batch * N_PER_BATCH);
    const int base = chunk * ROWS_PER_BLOCK + threadIdx.x;

    double s0 = 0, s1 = 0, s2 = 0, s3 = 0;
    double p00 = 0, p01 = 0, p02 = 0, p03 = 0;
    double p11 = 0, p12 = 0, p13 = 0;
    double p22 = 0, p23 = 0, p33 = 0;

    #pragma unroll 4
    for (int k = 0; k < ROWS_PER_THREAD; ++k) {
        float4 v = src[base + k * 256];
        double a = (double)v.x, b = (double)v.y, c = (double)v.z, d = (double)v.w;
        s0 += a; s1 += b; s2 += c; s3 += d;
        p00 += a * a; p01 += a * b; p02 += a * c; p03 += a * d;
        p11 += b * b; p12 += b * c; p13 += b * d;
        p22 += c * c; p23 += c * d; p33 += d * d;
    }

    double vals[14] = {s0, s1, s2, s3, p00, p01, p02, p03, p11, p12, p13, p22, p23, p33};
    __shared__ double red[4][14];
    const int lane = threadIdx.x & 63;
    const int wave = threadIdx.x >> 6;
    #pragma unroll
    for (int i = 0; i < 14; ++i) {
        double r = wave_reduce_add(vals[i]);
        if (lane == 0) red[wave][i] = r;
    }
    __syncthreads();
    if (threadIdx.x < 14) {
        partials[(size_t)blockIdx.x * 14 + threadIdx.x] =
            red[0][threadIdx.x] + red[1][threadIdx.x] +
            red[2][threadIdx.x] + red[3][threadIdx.x];
    }
}

// One block per batch (32 blocks, 64 threads): wave-reduce 64 partial sets,
// then lane 0 solves the 4x4 eigenproblem and emits projection weights.
__global__ __launch_bounds__(64) void eigen_kernel(const double* __restrict__ partials,
                                                   float* __restrict__ wb) {
    const int b = blockIdx.x;
    const double* p = partials + ((size_t)b * 64 + threadIdx.x) * 14;

    double a[14];
    #pragma unroll
    for (int i = 0; i < 14; ++i) a[i] = wave_reduce_add(p[i]);

    if (threadIdx.x != 0) return;

    const double N = (double)ROWS_PER_BATCH;
    double sum[4] = {a[0], a[1], a[2], a[3]};
    double S[4][4];
    S[0][0] = a[4];  S[0][1] = S[1][0] = a[5];  S[0][2] = S[2][0] = a[6];  S[0][3] = S[3][0] = a[7];
    S[1][1] = a[8];  S[1][2] = S[2][1] = a[9];  S[1][3] = S[3][1] = a[10];
    S[2][2] = a[11]; S[2][3] = S[3][2] = a[12]; S[3][3] = a[13];

    double m[4], sd[4], dn[4];
    #pragma unroll
    for (int j = 0; j < 4; ++j) {
        m[j] = sum[j] / N;
        double var = S[j][j] / N - m[j] * m[j];
        if (var < 0.0) var = 0.0;
        sd[j] = sqrt(var);
        dn[j] = (sd[j] == 0.0) ? 1.0 : sd[j];
    }

    // E = A - I in f32, where A = gram/N of normalized columns.
    // Same eigenvectors as A; diag: live column -> 0, dead column -> -1.
    float E[4][4];
    #pragma unroll
    for (int j = 0; j < 4; ++j)
        #pragma unroll
        for (int k = 0; k < 4; ++k) {
            double Ajk;
            if (sd[j] == 0.0 || sd[k] == 0.0) Ajk = 0.0;
            else Ajk = (S[j][k] / N - m[j] * m[k]) / (dn[j] * dn[k]);
            E[j][k] = (float)(Ajk - (j == k ? 1.0 : 0.0));
        }

    // Cyclic Jacobi, f32 (hw rcp/sqrt). |offdiag|~2e-3: quadratic convergence,
    // below f32 eps in <=3 sweeps; 4 for margin.
    float V[4][4] = {{1, 0, 0, 0}, {0, 1, 0, 0}, {0, 0, 1, 0}, {0, 0, 0, 1}};
    for (int sweep = 0; sweep < 4; ++sweep) {
        for (int pp = 0; pp < 3; ++pp) {
            for (int q = pp + 1; q < 4; ++q) {
                float apq = E[pp][q];
                if (fabsf(apq) < 1e-30f) continue;
                float theta = (E[q][q] - E[pp][pp]) / (2.0f * apq);
                float t = copysignf(1.0f, theta) / (fabsf(theta) + sqrtf(theta * theta + 1.0f));
                float c = 1.0f / sqrtf(t * t + 1.0f);
                float s = t * c;
                for (int k = 0; k < 4; ++k) {
                    float t1 = E[k][pp], t2 = E[k][q];
                    E[k][pp] = c * t1 - s * t2;
                    E[k][q]  = s * t1 + c * t2;
                }
                for (int k = 0; k < 4; ++k) {
                    float t1 = E[pp][k], t2 = E[q][k];
                    E[pp][k] = c * t1 - s * t2;
                    E[q][k]  = s * t1 + c * t2;
                }
                for (int k = 0; k < 4; ++k) {
                    float t1 = V[k][pp], t2 = V[k][q];
                    V[k][pp] = c * t1 - s * t2;
                    V[k][q]  = s * t1 + c * t2;
                }
            }
        }
    }

    int jmax = 0;
    float emax = E[0][0];
    for (int j = 1; j < 4; ++j)
        if (E[j][j] > emax) { emax = E[j][j]; jmax = j; }
    float v[4] = {V[0][jmax], V[1][jmax], V[2][jmax], V[3][jmax]};
    float sv = v[0] + v[1] + v[2] + v[3];
    if (sv < 0.0f) { v[0] = -v[0]; v[1] = -v[1]; v[2] = -v[2]; v[3] = -v[3]; }

    double w[4], bias = 0.0;
    #pragma unroll
    for (int j = 0; j < 4; ++j) {
        w[j] = (sd[j] == 0.0) ? 0.0 : (double)v[j] / dn[j];
        bias -= w[j] * m[j];
    }
    float* o = wb + b * 8;
    o[0] = (float)w[0]; o[1] = (float)w[1]; o[2] = (float)w[2]; o[3] = (float)w[3];
    o[4] = (float)bias;
}

// One thread -> 4 consecutive output channels (one float4 store),
// consuming 16 consecutive input channels (4 float4 loads, 64B contiguous).
__global__ __launch_bounds__(256) void proj_kernel(const float* __restrict__ in,
                                                   const float* __restrict__ wb,
                                                   float4* __restrict__ out) {
    const int t = blockIdx.x * 256 + threadIdx.x;   // 2,097,152 threads
    const int b  = t >> 16;                          // 65536 float4-outputs per batch
    const int r4 = t & 65535;
    const int i0 = r4 >> 10;                         // pooled row
    const int i1 = (r4 >> 4) & 63;                   // pooled col
    const int c0 = (r4 & 15) * 4;                    // first output channel
    const int i2 = c0 >> 5;
    const int i3 = (c0 >> 4) & 1;
    const int g0 = c0 & 15;                          // channel-group start

    const float* src = in + (size_t)(((b * 128 + 2 * i0 + i2) * 128) + (2 * i1 + i3)) * 64
                          + 4 * g0;
    const float4* s4 = (const float4*)src;
    float4 x0 = s4[0], x1 = s4[1], x2 = s4[2], x3 = s4[3];

    const float* p = wb + b * 8;
    float w0 = p[0], w1 = p[1], w2 = p[2], w3 = p[3], bias = p[4];

    float4 o;
    o.x = fmaf(w0, x0.x, fmaf(w1, x0.y, fmaf(w2, x0.z, fmaf(w3, x0.w, bias))));
    o.y = fmaf(w0, x1.x, fmaf(w1, x1.y, fmaf(w2, x1.z, fmaf(w3, x1.w, bias))));
    o.z = fmaf(w0, x2.x, fmaf(w1, x2.y, fmaf(w2, x2.z, fmaf(w3, x2.w, bias))));
    o.w = fmaf(w0, x3.x, fmaf(w1, x3.y, fmaf(w2, x3.z, fmaf(w3, x3.w, bias))));
    out[t] = o;
}

extern "C" void kernel_launch(void* const* d_in, const int* in_sizes, int n_in,
                              void* d_out, int out_size, void* d_ws, size_t ws_size,
                              hipStream_t stream) {
    const float* in = (const float*)d_in[0];
    float4* out = (float4*)d_out;
    double* partials = (double*)d_ws;
    float* wb = (float*)((char*)d_ws + WB_OFFSET);

    stats_kernel<<<NBATCH * BLOCKS_PER_BATCH, 256, 0, stream>>>(in, partials);
    eigen_kernel<<<NBATCH, 64, 0, stream>>>(partials, wb);
    proj_kernel<<<(NBATCH * ROWS_PER_BATCH / 4) / 256, 256, 0, stream>>>(in, wb, (float4*)out);
}